// Round 9
// baseline (185.859 us; speedup 1.0000x reference)
//
#include <hip/hip_runtime.h>
#include <cstdint>

#define NN    1024
#define MM    32
#define NEDGE 32240
#define MROWS 64480   // 2*NEDGE

typedef unsigned short ushort_t;

typedef __bf16 bf16x8 __attribute__((ext_vector_type(8)));
typedef float  floatx4 __attribute__((ext_vector_type(4)));

__device__ __forceinline__ float b2f(ushort_t u) {
    union { unsigned int i; float f; } v; v.i = ((unsigned int)u) << 16; return v.f;
}
__device__ __forceinline__ ushort_t f2b(float f) {
    unsigned int u = __builtin_bit_cast(unsigned int, f);
    u = (u + 0x7FFFu + ((u >> 16) & 1u)) >> 16;
    return (ushort_t)u;
}
__device__ __forceinline__ bf16x8 cvt8(float4 a, float4 b) {
    union { bf16x8 v; ushort_t u[8]; } r;
    r.u[0] = f2b(a.x); r.u[1] = f2b(a.y); r.u[2] = f2b(a.z); r.u[3] = f2b(a.w);
    r.u[4] = f2b(b.x); r.u[5] = f2b(b.y); r.u[6] = f2b(b.z); r.u[7] = f2b(b.w);
    return r.v;
}
// K(i): number of edges before node i
__device__ __forceinline__ int edge_base(int i) {
    return (i <= MM) ? ((i * (i - 1)) >> 1) : (496 + (i - MM) * MM);
}
// edge id e -> (dest i, src j)   [validated round 3; used only in pack]
__device__ __forceinline__ void edge_ij(int e, int& i, int& j) {
    if (e < 496) {
        i = (int)((1.0f + sqrtf(8.0f * (float)e + 1.0f)) * 0.5f);
        while (((i * (i - 1)) >> 1) > e) --i;
        while (((i * (i + 1)) >> 1) <= e) ++i;
        j = e - ((i * (i - 1)) >> 1);
    } else {
        int q = e - 496;
        i = MM + (q >> 5);
        j = i - MM + (q & 31);
    }
}

// ---------------- pack: LDS-tiled weight transpose + nodes bf16 + ein edge-cols + ij table ----------------
__global__ __launch_bounds__(256) void k_pack(
        const float* an1, const float* an2, const float* ae1, const float* ae2,
        const float* le1, const float* le2, const float* ln1, const float* ln2,
        const float* nodes, const float* edges,
        ushort_t* pan1, ushort_t* pan2, ushort_t* pae1, ushort_t* pae2,
        ushort_t* ple1, ushort_t* ple2, ushort_t* pln1, ushort_t* pln2,
        ushort_t* nodesb, ushort_t* ein, int2* ijt) {
    __shared__ float tile[32][33];
    const int bid = blockIdx.x;
    const int tid = threadIdx.x;
    if (bid < 152) {
        const float* s; ushort_t* d; int K, N, t;
        if (bid < 40)       { s = an1; d = pan1; K = 160; N = 256; t = bid;       }
        else if (bid < 72)  { s = an2; d = pan2; K = 256; N = 128; t = bid - 40;  }
        else if (bid < 84)  { s = ae1; d = pae1; K = 96;  N = 128; t = bid - 72;  }
        else if (bid < 92)  { s = ae2; d = pae2; K = 128; N = 64;  t = bid - 84;  }
        else if (bid < 101) { s = le1; d = ple1; K = 96;  N = 96;  t = bid - 92;  }
        else if (bid < 104) { s = le2; d = ple2; K = 96;  N = 32;  t = bid - 101; }
        else if (bid < 140) { s = ln1; d = pln1; K = 192; N = 192; t = bid - 104; }
        else                { s = ln2; d = pln2; K = 192; N = 64;  t = bid - 140; }
        int ntn = N >> 5;
        int tk = t / ntn, tn = t - tk * ntn;
        int k0 = tk * 32, n0 = tn * 32;
        int tx = tid & 31, ty = tid >> 5;
#pragma unroll
        for (int m = 0; m < 4; ++m)
            tile[ty + m * 8][tx] = s[(size_t)(k0 + ty + m * 8) * N + n0 + tx];
        __syncthreads();
#pragma unroll
        for (int m = 0; m < 4; ++m)
            d[(size_t)(n0 + ty + m * 8) * K + k0 + tx] = f2b(tile[tx][ty + m * 8]);
    } else if (bid < 280) {
        int i4 = (bid - 152) * 256 + tid;
        float4 v = ((const float4*)nodes)[i4];
        uint2 o;
        o.x = (unsigned)f2b(v.x) | ((unsigned)f2b(v.y) << 16);
        o.y = (unsigned)f2b(v.z) | ((unsigned)f2b(v.w) << 16);
        ((uint2*)nodesb)[i4] = o;
    } else if (bid < 2295) {
        int idx = (bid - 280) * 256 + tid;
        int r = idx >> 3, c4 = idx & 7;
        float4 v = ((const float4*)(edges + (size_t)r * 32))[c4];
        uint2 o;
        o.x = (unsigned)f2b(v.x) | ((unsigned)f2b(v.y) << 16);
        o.y = (unsigned)f2b(v.z) | ((unsigned)f2b(v.w) << 16);
        *(uint2*)(ein + (size_t)r * 96 + 64 + c4 * 4) = o;
    } else {
        int e = (bid - 2295) * 256 + tid;
        if (e < NEDGE) { int i, j; edge_ij(e, i, j); ijt[e] = make_int2(i, j); }
    }
}

// ---------------- agg: direct-A-fragment GEMM chains; node tiles [0,2015), edge [2015,4030) ----------------
// 512 threads = 8 waves. No gather / no X-tile: A-fragments loaded straight from global
// (lane layout A[m=lrow][k=lq*8+j] matches row-contiguous nodesb/edges rows).
__global__ __launch_bounds__(512, 4) void k_agg(
        const ushort_t* __restrict__ nodesb, const float* __restrict__ edges,
        const int2* __restrict__ ijt,
        const ushort_t* __restrict__ pan1, const float* __restrict__ ban1,
        const ushort_t* __restrict__ pan2, const float* __restrict__ ban2,
        const ushort_t* __restrict__ pae1, const float* __restrict__ bae1,
        const ushort_t* __restrict__ pae2, const float* __restrict__ bae2,
        ushort_t* __restrict__ hn, ushort_t* __restrict__ he) {
    __shared__ alignas(16) ushort_t LS[32 * 264];   // node: H1n (pitch 264) / edge: H1e (pitch 136)
    const int tid = threadIdx.x;
    const int w = tid >> 6, l = tid & 63, lrow = l & 15, lq = l >> 4;
    floatx4 zero = {0.f, 0.f, 0.f, 0.f};

    if (blockIdx.x < 2015) {
        const int mt = blockIdx.x;
        // A fragments (triples: [nodes[j] | edge | nodes[i]]), direct from global
        bf16x8 A[2][5];
#pragma unroll
        for (int s = 0; s < 2; ++s) {
            int r = mt * 32 + s * 16 + lrow;
            int off = (r >= NEDGE) ? NEDGE : 0;
            int2 ij = ijt[r - off];
            int bN = off ? NN : 0;
            const ushort_t* nj = nodesb + (size_t)(bN + ij.y) * 64;
            const ushort_t* ni = nodesb + (size_t)(bN + ij.x) * 64;
            A[s][0] = *(const bf16x8*)(nj + lq * 8);
            A[s][1] = *(const bf16x8*)(nj + 32 + lq * 8);
            const float* er = edges + (size_t)r * 32 + lq * 8;
            A[s][2] = cvt8(*(const float4*)er, *(const float4*)(er + 4));
            A[s][3] = *(const bf16x8*)(ni + lq * 8);
            A[s][4] = *(const bf16x8*)(ni + 32 + lq * 8);
        }
        // an1: 160 -> 256, wave cols w*32 (NT=2, KT=5)
        bf16x8 b1[5][2]; float v1[2];
#pragma unroll
        for (int kt = 0; kt < 5; ++kt)
#pragma unroll
            for (int nt = 0; nt < 2; ++nt)
                b1[kt][nt] = *(const bf16x8*)(pan1 + (size_t)(w * 32 + nt * 16 + lrow) * 160 + kt * 32 + lq * 8);
#pragma unroll
        for (int nt = 0; nt < 2; ++nt) v1[nt] = ban1[w * 32 + nt * 16 + lrow];

        floatx4 acc[2][2];
#pragma unroll
        for (int s = 0; s < 2; ++s) { acc[s][0] = zero; acc[s][1] = zero; }
#pragma unroll
        for (int s = 0; s < 2; ++s)
#pragma unroll
            for (int kt = 0; kt < 5; ++kt)
#pragma unroll
                for (int nt = 0; nt < 2; ++nt)
                    acc[s][nt] = __builtin_amdgcn_mfma_f32_16x16x32_bf16(A[s][kt], b1[kt][nt], acc[s][nt], 0, 0, 0);
#pragma unroll
        for (int s = 0; s < 2; ++s)
#pragma unroll
            for (int nt = 0; nt < 2; ++nt) {
                int col = w * 32 + nt * 16 + lrow;
#pragma unroll
                for (int r_ = 0; r_ < 4; ++r_)
                    LS[(s * 16 + lq * 4 + r_) * 264 + col] = f2b(fmaxf(acc[s][nt][r_] + v1[nt], 0.f));
            }
        // an2 B-frags before the barrier (latency overlap): cols w*16 (NT=1, KT=8)
        bf16x8 b2[8];
#pragma unroll
        for (int kt = 0; kt < 8; ++kt)
            b2[kt] = *(const bf16x8*)(pan2 + (size_t)(w * 16 + lrow) * 256 + kt * 32 + lq * 8);
        float v2 = ban2[w * 16 + lrow];
        __syncthreads();

        floatx4 a2[2] = {zero, zero};
#pragma unroll
        for (int s = 0; s < 2; ++s)
#pragma unroll
            for (int kt = 0; kt < 8; ++kt) {
                bf16x8 a = *(const bf16x8*)&LS[(s * 16 + lrow) * 264 + kt * 32 + lq * 8];
                a2[s] = __builtin_amdgcn_mfma_f32_16x16x32_bf16(a, b2[kt], a2[s], 0, 0, 0);
            }
#pragma unroll
        for (int s = 0; s < 2; ++s) {
            int col = w * 16 + lrow;
#pragma unroll
            for (int r_ = 0; r_ < 4; ++r_)
                hn[(size_t)(mt * 32 + s * 16 + lq * 4 + r_) * 128 + col] = f2b(fmaxf(a2[s][r_] + v2, 0.f));
        }
    } else {
        const int mt = blockIdx.x - 2015;
        // A fragments (pairs: [nodes[j] | edge])
        bf16x8 A[2][3];
#pragma unroll
        for (int s = 0; s < 2; ++s) {
            int r = mt * 32 + s * 16 + lrow;
            int off = (r >= NEDGE) ? NEDGE : 0;
            int2 ij = ijt[r - off];
            int bN = off ? NN : 0;
            const ushort_t* nj = nodesb + (size_t)(bN + ij.y) * 64;
            A[s][0] = *(const bf16x8*)(nj + lq * 8);
            A[s][1] = *(const bf16x8*)(nj + 32 + lq * 8);
            const float* er = edges + (size_t)r * 32 + lq * 8;
            A[s][2] = cvt8(*(const float4*)er, *(const float4*)(er + 4));
        }
        // ae1: 96 -> 128, wave cols w*16 (NT=1, KT=3)
        bf16x8 e1[3];
#pragma unroll
        for (int kt = 0; kt < 3; ++kt)
            e1[kt] = *(const bf16x8*)(pae1 + (size_t)(w * 16 + lrow) * 96 + kt * 32 + lq * 8);
        float v1 = bae1[w * 16 + lrow];

        floatx4 acc[2] = {zero, zero};
#pragma unroll
        for (int s = 0; s < 2; ++s)
#pragma unroll
            for (int kt = 0; kt < 3; ++kt)
                acc[s] = __builtin_amdgcn_mfma_f32_16x16x32_bf16(A[s][kt], e1[kt], acc[s], 0, 0, 0);
#pragma unroll
        for (int s = 0; s < 2; ++s) {
            int col = w * 16 + lrow;
#pragma unroll
            for (int r_ = 0; r_ < 4; ++r_)
                LS[(s * 16 + lq * 4 + r_) * 136 + col] = f2b(fmaxf(acc[s][r_] + v1, 0.f));
        }
        // ae2: 128 -> 64, waves 0-3 (NT=1, KT=4)
        bf16x8 e2[4]; float v2 = 0.f;
        if (w < 4) {
#pragma unroll
            for (int kt = 0; kt < 4; ++kt)
                e2[kt] = *(const bf16x8*)(pae2 + (size_t)(w * 16 + lrow) * 128 + kt * 32 + lq * 8);
            v2 = bae2[w * 16 + lrow];
        }
        __syncthreads();
        if (w < 4) {
            floatx4 a2[2] = {zero, zero};
#pragma unroll
            for (int s = 0; s < 2; ++s)
#pragma unroll
                for (int kt = 0; kt < 4; ++kt) {
                    bf16x8 a = *(const bf16x8*)&LS[(s * 16 + lrow) * 136 + kt * 32 + lq * 8];
                    a2[s] = __builtin_amdgcn_mfma_f32_16x16x32_bf16(a, e2[kt], a2[s], 0, 0, 0);
                }
#pragma unroll
            for (int s = 0; s < 2; ++s) {
                int col = w * 16 + lrow;
#pragma unroll
                for (int r_ = 0; r_ < 4; ++r_)
                    he[(size_t)(mt * 32 + s * 16 + lq * 4 + r_) * 64 + col] = f2b(fmaxf(a2[s][r_] + v2, 0.f));
            }
        }
    }
}

// ---------------- mid: pn = window-parallel mean(hn) | ein prefix cols, blockIdx split ----------------
__global__ __launch_bounds__(256) void k_mid(
        const ushort_t* __restrict__ hn, const ushort_t* __restrict__ he,
        ushort_t* __restrict__ pn, ushort_t* __restrict__ ein) {
    const int tid = threadIdx.x;
    if (blockIdx.x < 2048) {
        // block per node row: 4 row-groups sum in parallel, LDS reduce
        int ri = blockIdx.x;
        int b = ri >> 10, i = ri & 1023;
        int t = min(i, MM);
        int base = b * NEDGE + edge_base(i);
        int c = tid & 63, g = tid >> 6;
        float s0 = 0.f, s1 = 0.f;
        for (int p = g; p < t; p += 4) {
            unsigned u = ((const unsigned*)(hn + (size_t)(base + p) * 128))[c];
            s0 += b2f((ushort_t)(u & 0xffff));
            s1 += b2f((ushort_t)(u >> 16));
        }
        __shared__ float red[4][128];
        red[g][c * 2] = s0; red[g][c * 2 + 1] = s1;
        __syncthreads();
        if (tid < 64) {
            float inv = 1.0f / (float)max(t, 1);
            float a0 = (red[0][tid * 2] + red[1][tid * 2] + red[2][tid * 2] + red[3][tid * 2]) * inv;
            float a1 = (red[0][tid * 2 + 1] + red[1][tid * 2 + 1] + red[2][tid * 2 + 1] + red[3][tid * 2 + 1]) * inv;
            ((unsigned*)(pn + (size_t)ri * 128))[tid] = (unsigned)f2b(a0) | ((unsigned)f2b(a1) << 16);
        }
    } else {
        int bi = blockIdx.x - 2048;
        int b = bi >> 10, i = bi & 1023;
        int t = min(i, MM);
        if (t == 0) return;
        int base = b * NEDGE + edge_base(i);
        __shared__ alignas(16) ushort_t hw[32 * 64];
        for (int u = tid; u < t * 8; u += 256)
            ((uint4*)hw)[u] = ((const uint4*)he)[(size_t)base * 8 + u];
        __syncthreads();
        if (tid < 64) {
            float run = 0.f;
            for (int p = 0; p < t; ++p) {
                float v = (p == 0) ? 0.f : run / (float)p;
                ein[(size_t)(base + p) * 96 + tid] = f2b(v);
                run += b2f(hw[p * 64 + tid]);
            }
        }
    }
}

// ---------------- final: node MLP ([pn|nodesb] 192->192->64) | le12 (96->96->32), direct-A ----------------
__global__ __launch_bounds__(192) void k_final(
        const ushort_t* __restrict__ pn, const ushort_t* __restrict__ nodesb,
        const ushort_t* __restrict__ pln1, const float* __restrict__ bln1,
        const ushort_t* __restrict__ pln2, const float* __restrict__ bln2,
        float* __restrict__ out_nodes,
        const ushort_t* __restrict__ ein, const ushort_t* __restrict__ ple1,
        const float* __restrict__ ble1, const ushort_t* __restrict__ ple2,
        const float* __restrict__ ble2, float* __restrict__ out_edges) {
    __shared__ alignas(16) ushort_t LB[32 * 200];
    const int tid = threadIdx.x;
    const int w = tid >> 6, l = tid & 63, lrow = l & 15, lq = l >> 4;
    floatx4 zero = {0.f, 0.f, 0.f, 0.f};

    if (blockIdx.x < 64) {
        int tile = blockIdx.x;
        // A direct: rows of [pn | nodesb] (both row-contiguous at row index ri)
        bf16x8 A[2][6];
#pragma unroll
        for (int s = 0; s < 2; ++s) {
            int r = tile * 32 + s * 16 + lrow;
#pragma unroll
            for (int kt = 0; kt < 4; ++kt)
                A[s][kt] = *(const bf16x8*)(pn + (size_t)r * 128 + kt * 32 + lq * 8);
#pragma unroll
            for (int kt = 4; kt < 6; ++kt)
                A[s][kt] = *(const bf16x8*)(nodesb + (size_t)r * 64 + (kt - 4) * 32 + lq * 8);
        }
        bf16x8 f1[6][4]; float v1[4];
#pragma unroll
        for (int kt = 0; kt < 6; ++kt)
#pragma unroll
            for (int nt = 0; nt < 4; ++nt)
                f1[kt][nt] = *(const bf16x8*)(pln1 + (size_t)(w * 64 + nt * 16 + lrow) * 192 + kt * 32 + lq * 8);
#pragma unroll
        for (int nt = 0; nt < 4; ++nt) v1[nt] = bln1[w * 64 + nt * 16 + lrow];

        floatx4 acc[2][4];
#pragma unroll
        for (int s = 0; s < 2; ++s)
#pragma unroll
            for (int nt = 0; nt < 4; ++nt) acc[s][nt] = zero;
#pragma unroll
        for (int s = 0; s < 2; ++s)
#pragma unroll
            for (int kt = 0; kt < 6; ++kt)
#pragma unroll
                for (int nt = 0; nt < 4; ++nt)
                    acc[s][nt] = __builtin_amdgcn_mfma_f32_16x16x32_bf16(A[s][kt], f1[kt][nt], acc[s][nt], 0, 0, 0);
#pragma unroll
        for (int s = 0; s < 2; ++s)
#pragma unroll
            for (int nt = 0; nt < 4; ++nt) {
                int col = w * 64 + nt * 16 + lrow;
#pragma unroll
                for (int r_ = 0; r_ < 4; ++r_)
                    LB[(s * 16 + lq * 4 + r_) * 200 + col] = f2b(fmaxf(acc[s][nt][r_] + v1[nt], 0.f));
            }
        bf16x8 f2[6][2]; float v2[2] = {0.f, 0.f};
        if (w < 2) {
#pragma unroll
            for (int kt = 0; kt < 6; ++kt)
#pragma unroll
                for (int nt = 0; nt < 2; ++nt)
                    f2[kt][nt] = *(const bf16x8*)(pln2 + (size_t)(w * 32 + nt * 16 + lrow) * 192 + kt * 32 + lq * 8);
#pragma unroll
            for (int nt = 0; nt < 2; ++nt) v2[nt] = bln2[w * 32 + nt * 16 + lrow];
        }
        __syncthreads();
        if (w < 2) {
            floatx4 a2[2][2];
#pragma unroll
            for (int s = 0; s < 2; ++s) { a2[s][0] = zero; a2[s][1] = zero; }
#pragma unroll
            for (int s = 0; s < 2; ++s)
#pragma unroll
                for (int kt = 0; kt < 6; ++kt) {
                    bf16x8 a = *(const bf16x8*)&LB[(s * 16 + lrow) * 200 + kt * 32 + lq * 8];
#pragma unroll
                    for (int nt = 0; nt < 2; ++nt)
                        a2[s][nt] = __builtin_amdgcn_mfma_f32_16x16x32_bf16(a, f2[kt][nt], a2[s][nt], 0, 0, 0);
                }
#pragma unroll
            for (int s = 0; s < 2; ++s)
#pragma unroll
                for (int nt = 0; nt < 2; ++nt) {
                    int col = w * 32 + nt * 16 + lrow;
#pragma unroll
                    for (int r_ = 0; r_ < 4; ++r_)
                        out_nodes[(size_t)(tile * 32 + s * 16 + lq * 4 + r_) * 64 + col] =
                            fmaxf(a2[s][nt][r_] + v2[nt], 0.f);
                }
        }
    } else {
        int mt = blockIdx.x - 64;
        // A direct from ein rows (pitch 96)
        bf16x8 A[2][3];
#pragma unroll
        for (int s = 0; s < 2; ++s) {
            int r = mt * 32 + s * 16 + lrow;
#pragma unroll
            for (int kt = 0; kt < 3; ++kt)
                A[s][kt] = *(const bf16x8*)(ein + (size_t)r * 96 + kt * 32 + lq * 8);
        }
        bf16x8 fb1[3][2]; float v1[2];
#pragma unroll
        for (int kt = 0; kt < 3; ++kt)
#pragma unroll
            for (int nt = 0; nt < 2; ++nt)
                fb1[kt][nt] = *(const bf16x8*)(ple1 + (size_t)(w * 32 + nt * 16 + lrow) * 96 + kt * 32 + lq * 8);
#pragma unroll
        for (int nt = 0; nt < 2; ++nt) v1[nt] = ble1[w * 32 + nt * 16 + lrow];

        floatx4 acc[2][2];
#pragma unroll
        for (int s = 0; s < 2; ++s) { acc[s][0] = zero; acc[s][1] = zero; }
#pragma unroll
        for (int s = 0; s < 2; ++s)
#pragma unroll
            for (int kt = 0; kt < 3; ++kt)
#pragma unroll
                for (int nt = 0; nt < 2; ++nt)
                    acc[s][nt] = __builtin_amdgcn_mfma_f32_16x16x32_bf16(A[s][kt], fb1[kt][nt], acc[s][nt], 0, 0, 0);
#pragma unroll
        for (int s = 0; s < 2; ++s)
#pragma unroll
            for (int nt = 0; nt < 2; ++nt) {
                int col = w * 32 + nt * 16 + lrow;
#pragma unroll
                for (int r_ = 0; r_ < 4; ++r_)
                    LB[(s * 16 + lq * 4 + r_) * 104 + col] = f2b(fmaxf(acc[s][nt][r_] + v1[nt], 0.f));
            }
        bf16x8 fb2[3]; float v2 = 0.f;
        if (w < 2) {
#pragma unroll
            for (int kt = 0; kt < 3; ++kt)
                fb2[kt] = *(const bf16x8*)(ple2 + (size_t)(w * 16 + lrow) * 96 + kt * 32 + lq * 8);
            v2 = ble2[w * 16 + lrow];
        }
        __syncthreads();
        if (w < 2) {
            floatx4 a2[2] = {zero, zero};
#pragma unroll
            for (int s = 0; s < 2; ++s)
#pragma unroll
                for (int kt = 0; kt < 3; ++kt) {
                    bf16x8 a = *(const bf16x8*)&LB[(s * 16 + lrow) * 104 + kt * 32 + lq * 8];
                    a2[s] = __builtin_amdgcn_mfma_f32_16x16x32_bf16(a, fb2[kt], a2[s], 0, 0, 0);
                }
#pragma unroll
            for (int s = 0; s < 2; ++s) {
                int col = w * 16 + lrow;
#pragma unroll
                for (int r_ = 0; r_ < 4; ++r_)
                    out_edges[(size_t)(mt * 32 + s * 16 + lq * 4 + r_) * 32 + col] = fmaxf(a2[s][r_] + v2, 0.f);
            }
        }
    }
}

extern "C" void kernel_launch(void* const* d_in, const int* in_sizes, int n_in,
                              void* d_out, int out_size, void* d_ws, size_t ws_size,
                              hipStream_t stream) {
    const float* nodes = (const float*)d_in[0];
    const float* edges = (const float*)d_in[1];
    const float* Wan1 = (const float*)d_in[2];  const float* ban1 = (const float*)d_in[3];
    const float* Wan2 = (const float*)d_in[4];  const float* ban2 = (const float*)d_in[5];
    const float* Wln1 = (const float*)d_in[6];  const float* bln1 = (const float*)d_in[7];
    const float* Wln2 = (const float*)d_in[8];  const float* bln2 = (const float*)d_in[9];
    const float* Wae1 = (const float*)d_in[10]; const float* bae1 = (const float*)d_in[11];
    const float* Wae2 = (const float*)d_in[12]; const float* bae2 = (const float*)d_in[13];
    const float* Wle1 = (const float*)d_in[14]; const float* ble1 = (const float*)d_in[15];
    const float* Wle2 = (const float*)d_in[16]; const float* ble2 = (const float*)d_in[17];

    char* ws = (char*)d_ws;
    size_t o = 0;
    auto alloc = [&](size_t bytes) -> void* {
        void* r = ws + o;
        o += (bytes + 255) & ~(size_t)255;
        return r;
    };
    ushort_t* hn     = (ushort_t*)alloc((size_t)MROWS * 128 * 2);
    ushort_t* he     = (ushort_t*)alloc((size_t)MROWS * 64 * 2);
    ushort_t* ein    = (ushort_t*)alloc((size_t)MROWS * 96 * 2);
    ushort_t* pn     = (ushort_t*)alloc((size_t)2048 * 128 * 2);
    ushort_t* nodesb = (ushort_t*)alloc((size_t)2 * NN * 64 * 2);
    int2*     ijt    = (int2*)alloc((size_t)NEDGE * 8);
    ushort_t* pan1 = (ushort_t*)alloc(160 * 256 * 2);
    ushort_t* pan2 = (ushort_t*)alloc(256 * 128 * 2);
    ushort_t* pae1 = (ushort_t*)alloc(96 * 128 * 2);
    ushort_t* pae2 = (ushort_t*)alloc(128 * 64 * 2);
    ushort_t* ple1 = (ushort_t*)alloc(96 * 96 * 2);
    ushort_t* ple2 = (ushort_t*)alloc(96 * 32 * 2);
    ushort_t* pln1 = (ushort_t*)alloc(192 * 192 * 2);
    ushort_t* pln2 = (ushort_t*)alloc(192 * 64 * 2);

    float* out_nodes = (float*)d_out;
    float* out_edges = (float*)d_out + 2 * NN * 64;

    k_pack<<<2421, 256, 0, stream>>>(Wan1, Wan2, Wae1, Wae2, Wle1, Wle2, Wln1, Wln2,
                                     nodes, edges,
                                     pan1, pan2, pae1, pae2, ple1, ple2, pln1, pln2,
                                     nodesb, ein, ijt);
    k_agg<<<4030, 512, 0, stream>>>(nodesb, edges, ijt,
                                    pan1, ban1, pan2, ban2,
                                    pae1, bae1, pae2, bae2, hn, he);
    k_mid<<<4096, 256, 0, stream>>>(hn, he, pn, ein);
    k_final<<<64 + 2015, 192, 0, stream>>>(pn, nodesb, pln1, bln1, pln2, bln2, out_nodes,
                                           ein, ple1, ble1, ple2, ble2, out_edges);

    (void)in_sizes; (void)n_in; (void)out_size; (void)ws_size;
}

// Round 10
// 169.649 us; speedup vs baseline: 1.0955x; 1.0955x over previous
//
#include <hip/hip_runtime.h>
#include <cstdint>

#define NN    1024
#define MM    32
#define NEDGE 32240
#define MROWS 64480   // 2*NEDGE
#define PX    168     // X tile pitch (ushorts)
#define PST   392     // unified stage pitch: 256 (H1n) + 128 (H1e) + 8 pad

typedef unsigned short ushort_t;

typedef __bf16 bf16x8 __attribute__((ext_vector_type(8)));
typedef float  floatx4 __attribute__((ext_vector_type(4)));

__device__ __forceinline__ float b2f(ushort_t u) {
    union { unsigned int i; float f; } v; v.i = ((unsigned int)u) << 16; return v.f;
}
__device__ __forceinline__ ushort_t f2b(float f) {
    unsigned int u = __builtin_bit_cast(unsigned int, f);
    u = (u + 0x7FFFu + ((u >> 16) & 1u)) >> 16;
    return (ushort_t)u;
}
// K(i): number of edges before node i
__device__ __forceinline__ int edge_base(int i) {
    return (i <= MM) ? ((i * (i - 1)) >> 1) : (496 + (i - MM) * MM);
}
// edge id e -> (dest i, src j)   [validated round 3; used only in pack]
__device__ __forceinline__ void edge_ij(int e, int& i, int& j) {
    if (e < 496) {
        i = (int)((1.0f + sqrtf(8.0f * (float)e + 1.0f)) * 0.5f);
        while (((i * (i - 1)) >> 1) > e) --i;
        while (((i * (i + 1)) >> 1) <= e) ++i;
        j = e - ((i * (i - 1)) >> 1);
    } else {
        int q = e - 496;
        i = MM + (q >> 5);
        j = i - MM + (q & 31);
    }
}

// ---------------- pack: LDS-tiled weight transpose + nodes bf16 + ij table ----------------
__global__ __launch_bounds__(256) void k_pack(
        const float* an1, const float* an2, const float* ae1, const float* ae2,
        const float* le1, const float* le2, const float* ln1, const float* ln2,
        const float* nodes,
        ushort_t* pan1, ushort_t* pan2, ushort_t* pae1, ushort_t* pae2,
        ushort_t* ple1, ushort_t* ple2, ushort_t* pln1, ushort_t* pln2,
        ushort_t* nodesb, int2* ijt) {
    __shared__ float tile[32][33];
    const int bid = blockIdx.x;
    const int tid = threadIdx.x;
    if (bid < 152) {
        const float* s; ushort_t* d; int K, N, t;
        if (bid < 40)       { s = an1; d = pan1; K = 160; N = 256; t = bid;       }
        else if (bid < 72)  { s = an2; d = pan2; K = 256; N = 128; t = bid - 40;  }
        else if (bid < 84)  { s = ae1; d = pae1; K = 96;  N = 128; t = bid - 72;  }
        else if (bid < 92)  { s = ae2; d = pae2; K = 128; N = 64;  t = bid - 84;  }
        else if (bid < 101) { s = le1; d = ple1; K = 96;  N = 96;  t = bid - 92;  }
        else if (bid < 104) { s = le2; d = ple2; K = 96;  N = 32;  t = bid - 101; }
        else if (bid < 140) { s = ln1; d = pln1; K = 192; N = 192; t = bid - 104; }
        else                { s = ln2; d = pln2; K = 192; N = 64;  t = bid - 140; }
        int ntn = N >> 5;
        int tk = t / ntn, tn = t - tk * ntn;
        int k0 = tk * 32, n0 = tn * 32;
        int tx = tid & 31, ty = tid >> 5;
#pragma unroll
        for (int m = 0; m < 4; ++m)
            tile[ty + m * 8][tx] = s[(size_t)(k0 + ty + m * 8) * N + n0 + tx];
        __syncthreads();
#pragma unroll
        for (int m = 0; m < 4; ++m)
            d[(size_t)(n0 + ty + m * 8) * K + k0 + tx] = f2b(tile[tx][ty + m * 8]);
    } else if (bid < 280) {
        int i4 = (bid - 152) * 256 + tid;
        float4 v = ((const float4*)nodes)[i4];
        uint2 o;
        o.x = (unsigned)f2b(v.x) | ((unsigned)f2b(v.y) << 16);
        o.y = (unsigned)f2b(v.z) | ((unsigned)f2b(v.w) << 16);
        ((uint2*)nodesb)[i4] = o;
    } else {
        int e = (bid - 280) * 256 + tid;
        if (e < NEDGE) { int i, j; edge_ij(e, i, j); ijt[e] = make_int2(i, j); }
    }
}

// ---------------- agg: merged node+edge branches, one block per 32-row tile ----------------
// 512 thr = 8 waves. Stage1: wave w computes an1 tiles {w, w+8} + ae1 tile {w} from shared X.
// Stage2: waves 0-3 an2 tiles {w, w+4}; waves 4-7 ae2 tile {w-4}. X gathered ONCE (round-8 proven idiom).
__global__ __launch_bounds__(512, 2) void k_agg(
        const ushort_t* __restrict__ nodesb, const float* __restrict__ edges,
        const int2* __restrict__ ijt,
        const ushort_t* __restrict__ pan1, const float* __restrict__ ban1,
        const ushort_t* __restrict__ pan2, const float* __restrict__ ban2,
        const ushort_t* __restrict__ pae1, const float* __restrict__ bae1,
        const ushort_t* __restrict__ pae2, const float* __restrict__ bae2,
        ushort_t* __restrict__ hn, ushort_t* __restrict__ he) {
    __shared__ alignas(16) ushort_t X[32 * PX];     // [nodes[j] | edge | nodes[i]] tile
    __shared__ alignas(16) ushort_t H[32 * PST];    // [H1n 0..255 | H1e 256..383]
    const int tid = threadIdx.x;
    const int w = tid >> 6, l = tid & 63, lrow = l & 15, lq = l >> 4;
    const int mt = blockIdx.x;
    floatx4 zero = {0.f, 0.f, 0.f, 0.f};

    // ---- stage-1 B fragments (issued before gather for latency overlap) ----
    bf16x8 B0[5], B1[5], B2[3];
#pragma unroll
    for (int kt = 0; kt < 5; ++kt) {
        B0[kt] = *(const bf16x8*)(pan1 + (size_t)(16 * w + lrow) * 160 + kt * 32 + lq * 8);
        B1[kt] = *(const bf16x8*)(pan1 + (size_t)(16 * (w + 8) + lrow) * 160 + kt * 32 + lq * 8);
    }
#pragma unroll
    for (int kt = 0; kt < 3; ++kt)
        B2[kt] = *(const bf16x8*)(pae1 + (size_t)(16 * w + lrow) * 96 + kt * 32 + lq * 8);
    float c0 = ban1[16 * w + lrow];
    float c1 = ban1[16 * (w + 8) + lrow];
    float c2 = bae1[16 * w + lrow];

    // ---- gather: wave w rows w*4..w*4+3, coalesced segments ----
#pragma unroll
    for (int k = 0; k < 4; ++k) {
        int rr = w * 4 + k;
        int r = mt * 32 + rr;
        int off = (r >= NEDGE) ? 1 : 0;
        int2 ij = ijt[r - off * NEDGE];
        int bN = off * NN;
        ushort_t* xr = X + rr * PX;
        const unsigned* nj = (const unsigned*)(nodesb + (size_t)(bN + ij.y) * 64);
        const unsigned* ni = (const unsigned*)(nodesb + (size_t)(bN + ij.x) * 64);
        if (l < 32) { ((unsigned*)xr)[l] = nj[l]; ((unsigned*)xr)[48 + l] = ni[l]; }
        else        xr[64 + (l - 32)] = f2b(edges[(size_t)r * 32 + (l - 32)]);
    }
    __syncthreads();

    // ---- stage 1: A shared per s across the wave's 3 tiles ----
#pragma unroll
    for (int s = 0; s < 2; ++s) {
        bf16x8 A[5];
#pragma unroll
        for (int kt = 0; kt < 5; ++kt)
            A[kt] = *(const bf16x8*)&X[(s * 16 + lrow) * PX + kt * 32 + lq * 8];
        floatx4 a0 = zero, a1 = zero, a2 = zero;
#pragma unroll
        for (int kt = 0; kt < 5; ++kt) {
            a0 = __builtin_amdgcn_mfma_f32_16x16x32_bf16(A[kt], B0[kt], a0, 0, 0, 0);
            a1 = __builtin_amdgcn_mfma_f32_16x16x32_bf16(A[kt], B1[kt], a1, 0, 0, 0);
        }
#pragma unroll
        for (int kt = 0; kt < 3; ++kt)
            a2 = __builtin_amdgcn_mfma_f32_16x16x32_bf16(A[kt], B2[kt], a2, 0, 0, 0);
#pragma unroll
        for (int r_ = 0; r_ < 4; ++r_) {
            int row = (s * 16 + lq * 4 + r_) * PST;
            H[row + 16 * w + lrow]       = f2b(fmaxf(a0[r_] + c0, 0.f));
            H[row + 128 + 16 * w + lrow] = f2b(fmaxf(a1[r_] + c1, 0.f));
            H[row + 256 + 16 * w + lrow] = f2b(fmaxf(a2[r_] + c2, 0.f));
        }
    }
    __syncthreads();

    // ---- stage 2 ----
    if (w < 4) {
        // an2: tiles u=w and u=w+4 (cols 16u of hn), KT=8, A shared
        bf16x8 D0[8], D1[8];
#pragma unroll
        for (int kt = 0; kt < 8; ++kt) {
            D0[kt] = *(const bf16x8*)(pan2 + (size_t)(16 * w + lrow) * 256 + kt * 32 + lq * 8);
            D1[kt] = *(const bf16x8*)(pan2 + (size_t)(16 * (w + 4) + lrow) * 256 + kt * 32 + lq * 8);
        }
        float d0 = ban2[16 * w + lrow];
        float d1 = ban2[16 * (w + 4) + lrow];
#pragma unroll
        for (int s = 0; s < 2; ++s) {
            floatx4 a0 = zero, a1 = zero;
#pragma unroll
            for (int kt = 0; kt < 8; ++kt) {
                bf16x8 a = *(const bf16x8*)&H[(s * 16 + lrow) * PST + kt * 32 + lq * 8];
                a0 = __builtin_amdgcn_mfma_f32_16x16x32_bf16(a, D0[kt], a0, 0, 0, 0);
                a1 = __builtin_amdgcn_mfma_f32_16x16x32_bf16(a, D1[kt], a1, 0, 0, 0);
            }
#pragma unroll
            for (int r_ = 0; r_ < 4; ++r_) {
                size_t row = (size_t)(mt * 32 + s * 16 + lq * 4 + r_) * 128;
                hn[row + 16 * w + lrow]       = f2b(fmaxf(a0[r_] + d0, 0.f));
                hn[row + 64 + 16 * w + lrow]  = f2b(fmaxf(a1[r_] + d1, 0.f));
            }
        }
    } else {
        // ae2: tile u=w-4 (cols 16(w-4) of he), KT=4, A from H cols 256..383
        int u = w - 4;
        bf16x8 E[4];
#pragma unroll
        for (int kt = 0; kt < 4; ++kt)
            E[kt] = *(const bf16x8*)(pae2 + (size_t)(16 * u + lrow) * 128 + kt * 32 + lq * 8);
        float d2 = bae2[16 * u + lrow];
#pragma unroll
        for (int s = 0; s < 2; ++s) {
            floatx4 a2 = zero;
#pragma unroll
            for (int kt = 0; kt < 4; ++kt) {
                bf16x8 a = *(const bf16x8*)&H[(s * 16 + lrow) * PST + 256 + kt * 32 + lq * 8];
                a2 = __builtin_amdgcn_mfma_f32_16x16x32_bf16(a, E[kt], a2, 0, 0, 0);
            }
#pragma unroll
            for (int r_ = 0; r_ < 4; ++r_)
                he[(size_t)(mt * 32 + s * 16 + lq * 4 + r_) * 64 + 16 * u + lrow] =
                    f2b(fmaxf(a2[r_] + d2, 0.f));
        }
    }
}

// ---------------- mid: pn = window-parallel mean(hn) | ein (prefix + edge cols), blockIdx split ----------------
__global__ __launch_bounds__(256) void k_mid(
        const ushort_t* __restrict__ hn, const ushort_t* __restrict__ he,
        const float* __restrict__ edges,
        ushort_t* __restrict__ pn, ushort_t* __restrict__ ein) {
    const int tid = threadIdx.x;
    if (blockIdx.x < 2048) {
        int ri = blockIdx.x;
        int b = ri >> 10, i = ri & 1023;
        int t = min(i, MM);
        int base = b * NEDGE + edge_base(i);
        int c = tid & 63, g = tid >> 6;
        float s0 = 0.f, s1 = 0.f;
        for (int p = g; p < t; p += 4) {
            unsigned u = ((const unsigned*)(hn + (size_t)(base + p) * 128))[c];
            s0 += b2f((ushort_t)(u & 0xffff));
            s1 += b2f((ushort_t)(u >> 16));
        }
        __shared__ float red[4][128];
        red[g][c * 2] = s0; red[g][c * 2 + 1] = s1;
        __syncthreads();
        if (tid < 64) {
            float inv = 1.0f / (float)max(t, 1);
            float a0 = (red[0][tid * 2] + red[1][tid * 2] + red[2][tid * 2] + red[3][tid * 2]) * inv;
            float a1 = (red[0][tid * 2 + 1] + red[1][tid * 2 + 1] + red[2][tid * 2 + 1] + red[3][tid * 2 + 1]) * inv;
            ((unsigned*)(pn + (size_t)ri * 128))[tid] = (unsigned)f2b(a0) | ((unsigned)f2b(a1) << 16);
        }
    } else {
        int bi = blockIdx.x - 2048;
        int b = bi >> 10, i = bi & 1023;
        int t = min(i, MM);
        if (t == 0) return;
        int base = b * NEDGE + edge_base(i);
        __shared__ alignas(16) ushort_t hw[32 * 64];
        for (int u = tid; u < t * 8; u += 256)
            ((uint4*)hw)[u] = ((const uint4*)he)[(size_t)base * 8 + u];
        __syncthreads();
        if (tid < 64) {
            float run = 0.f;
            for (int p = 0; p < t; ++p) {
                float v = (p == 0) ? 0.f : run / (float)p;
                ein[(size_t)(base + p) * 96 + tid] = f2b(v);
                run += b2f(hw[p * 64 + tid]);
            }
        } else if (tid < 96) {
            int c = tid - 64;
            for (int p = 0; p < t; ++p)
                ein[(size_t)(base + p) * 96 + 64 + c] = f2b(edges[(size_t)(base + p) * 32 + c]);
        }
    }
}

// ---------------- final: node MLP ([pn|nodesb] 192->192->64) | le12 (96->96->32) ----------------
__global__ __launch_bounds__(192) void k_final(
        const ushort_t* __restrict__ pn, const ushort_t* __restrict__ nodesb,
        const ushort_t* __restrict__ pln1, const float* __restrict__ bln1,
        const ushort_t* __restrict__ pln2, const float* __restrict__ bln2,
        float* __restrict__ out_nodes,
        const ushort_t* __restrict__ ein, const ushort_t* __restrict__ ple1,
        const float* __restrict__ ble1, const ushort_t* __restrict__ ple2,
        const float* __restrict__ ble2, float* __restrict__ out_edges) {
    __shared__ alignas(16) ushort_t LB[32 * 200];
    const int tid = threadIdx.x;
    const int w = tid >> 6, l = tid & 63, lrow = l & 15, lq = l >> 4;
    floatx4 zero = {0.f, 0.f, 0.f, 0.f};

    if (blockIdx.x < 64) {
        int tile = blockIdx.x;
        bf16x8 A[2][6];
#pragma unroll
        for (int s = 0; s < 2; ++s) {
            int r = tile * 32 + s * 16 + lrow;
#pragma unroll
            for (int kt = 0; kt < 4; ++kt)
                A[s][kt] = *(const bf16x8*)(pn + (size_t)r * 128 + kt * 32 + lq * 8);
#pragma unroll
            for (int kt = 4; kt < 6; ++kt)
                A[s][kt] = *(const bf16x8*)(nodesb + (size_t)r * 64 + (kt - 4) * 32 + lq * 8);
        }
        bf16x8 f1[6][4]; float v1[4];
#pragma unroll
        for (int kt = 0; kt < 6; ++kt)
#pragma unroll
            for (int nt = 0; nt < 4; ++nt)
                f1[kt][nt] = *(const bf16x8*)(pln1 + (size_t)(w * 64 + nt * 16 + lrow) * 192 + kt * 32 + lq * 8);
#pragma unroll
        for (int nt = 0; nt < 4; ++nt) v1[nt] = bln1[w * 64 + nt * 16 + lrow];

        floatx4 acc[2][4];
#pragma unroll
        for (int s = 0; s < 2; ++s)
#pragma unroll
            for (int nt = 0; nt < 4; ++nt) acc[s][nt] = zero;
#pragma unroll
        for (int s = 0; s < 2; ++s)
#pragma unroll
            for (int kt = 0; kt < 6; ++kt)
#pragma unroll
                for (int nt = 0; nt < 4; ++nt)
                    acc[s][nt] = __builtin_amdgcn_mfma_f32_16x16x32_bf16(A[s][kt], f1[kt][nt], acc[s][nt], 0, 0, 0);
#pragma unroll
        for (int s = 0; s < 2; ++s)
#pragma unroll
            for (int nt = 0; nt < 4; ++nt) {
                int col = w * 64 + nt * 16 + lrow;
#pragma unroll
                for (int r_ = 0; r_ < 4; ++r_)
                    LB[(s * 16 + lq * 4 + r_) * 200 + col] = f2b(fmaxf(acc[s][nt][r_] + v1[nt], 0.f));
            }
        bf16x8 f2[6][2]; float v2[2] = {0.f, 0.f};
        if (w < 2) {
#pragma unroll
            for (int kt = 0; kt < 6; ++kt)
#pragma unroll
                for (int nt = 0; nt < 2; ++nt)
                    f2[kt][nt] = *(const bf16x8*)(pln2 + (size_t)(w * 32 + nt * 16 + lrow) * 192 + kt * 32 + lq * 8);
#pragma unroll
            for (int nt = 0; nt < 2; ++nt) v2[nt] = bln2[w * 32 + nt * 16 + lrow];
        }
        __syncthreads();
        if (w < 2) {
            floatx4 a2[2][2];
#pragma unroll
            for (int s = 0; s < 2; ++s) { a2[s][0] = zero; a2[s][1] = zero; }
#pragma unroll
            for (int s = 0; s < 2; ++s)
#pragma unroll
                for (int kt = 0; kt < 6; ++kt) {
                    bf16x8 a = *(const bf16x8*)&LB[(s * 16 + lrow) * 200 + kt * 32 + lq * 8];
#pragma unroll
                    for (int nt = 0; nt < 2; ++nt)
                        a2[s][nt] = __builtin_amdgcn_mfma_f32_16x16x32_bf16(a, f2[kt][nt], a2[s][nt], 0, 0, 0);
                }
#pragma unroll
            for (int s = 0; s < 2; ++s)
#pragma unroll
                for (int nt = 0; nt < 2; ++nt) {
                    int col = w * 32 + nt * 16 + lrow;
#pragma unroll
                    for (int r_ = 0; r_ < 4; ++r_)
                        out_nodes[(size_t)(tile * 32 + s * 16 + lq * 4 + r_) * 64 + col] =
                            fmaxf(a2[s][nt][r_] + v2[nt], 0.f);
                }
        }
    } else {
        int mt = blockIdx.x - 64;
        bf16x8 A[2][3];
#pragma unroll
        for (int s = 0; s < 2; ++s) {
            int r = mt * 32 + s * 16 + lrow;
#pragma unroll
            for (int kt = 0; kt < 3; ++kt)
                A[s][kt] = *(const bf16x8*)(ein + (size_t)r * 96 + kt * 32 + lq * 8);
        }
        bf16x8 fb1[3][2]; float v1[2];
#pragma unroll
        for (int kt = 0; kt < 3; ++kt)
#pragma unroll
            for (int nt = 0; nt < 2; ++nt)
                fb1[kt][nt] = *(const bf16x8*)(ple1 + (size_t)(w * 32 + nt * 16 + lrow) * 96 + kt * 32 + lq * 8);
#pragma unroll
        for (int nt = 0; nt < 2; ++nt) v1[nt] = ble1[w * 32 + nt * 16 + lrow];

        floatx4 acc[2][2];
#pragma unroll
        for (int s = 0; s < 2; ++s) { acc[s][0] = zero; acc[s][1] = zero; }
#pragma unroll
        for (int s = 0; s < 2; ++s)
#pragma unroll
            for (int kt = 0; kt < 3; ++kt)
#pragma unroll
                for (int nt = 0; nt < 2; ++nt)
                    acc[s][nt] = __builtin_amdgcn_mfma_f32_16x16x32_bf16(A[s][kt], fb1[kt][nt], acc[s][nt], 0, 0, 0);
#pragma unroll
        for (int s = 0; s < 2; ++s)
#pragma unroll
            for (int nt = 0; nt < 2; ++nt) {
                int col = w * 32 + nt * 16 + lrow;
#pragma unroll
                for (int r_ = 0; r_ < 4; ++r_)
                    LB[(s * 16 + lq * 4 + r_) * 104 + col] = f2b(fmaxf(acc[s][nt][r_] + v1[nt], 0.f));
            }
        bf16x8 fb2[3]; float v2 = 0.f;
        if (w < 2) {
#pragma unroll
            for (int kt = 0; kt < 3; ++kt)
                fb2[kt] = *(const bf16x8*)(ple2 + (size_t)(w * 16 + lrow) * 96 + kt * 32 + lq * 8);
            v2 = ble2[w * 16 + lrow];
        }
        __syncthreads();
        if (w < 2) {
            floatx4 a2[2] = {zero, zero};
#pragma unroll
            for (int s = 0; s < 2; ++s)
#pragma unroll
                for (int kt = 0; kt < 3; ++kt) {
                    bf16x8 a = *(const bf16x8*)&LB[(s * 16 + lrow) * 104 + kt * 32 + lq * 8];
                    a2[s] = __builtin_amdgcn_mfma_f32_16x16x32_bf16(a, fb2[kt], a2[s], 0, 0, 0);
                }
#pragma unroll
            for (int s = 0; s < 2; ++s) {
                int col = w * 16 + lrow;
#pragma unroll
                for (int r_ = 0; r_ < 4; ++r_)
                    out_edges[(size_t)(mt * 32 + s * 16 + lq * 4 + r_) * 32 + col] = fmaxf(a2[s][r_] + v2, 0.f);
            }
        }
    }
}

extern "C" void kernel_launch(void* const* d_in, const int* in_sizes, int n_in,
                              void* d_out, int out_size, void* d_ws, size_t ws_size,
                              hipStream_t stream) {
    const float* nodes = (const float*)d_in[0];
    const float* edges = (const float*)d_in[1];
    const float* Wan1 = (const float*)d_in[2];  const float* ban1 = (const float*)d_in[3];
    const float* Wan2 = (const float*)d_in[4];  const float* ban2 = (const float*)d_in[5];
    const float* Wln1 = (const float*)d_in[6];  const float* bln1 = (const float*)d_in[7];
    const float* Wln2 = (const float*)d_in[8];  const float* bln2 = (const float*)d_in[9];
    const float* Wae1 = (const float*)d_in[10]; const float* bae1 = (const float*)d_in[11];
    const float* Wae2 = (const float*)d_in[12]; const float* bae2 = (const float*)d_in[13];
    const float* Wle1 = (const float*)d_in[14]; const float* ble1 = (const float*)d_in[15];
    const float* Wle2 = (const float*)d_in[16]; const float* ble2 = (const float*)d_in[17];

    char* ws = (char*)d_ws;
    size_t o = 0;
    auto alloc = [&](size_t bytes) -> void* {
        void* r = ws + o;
        o += (bytes + 255) & ~(size_t)255;
        return r;
    };
    ushort_t* hn     = (ushort_t*)alloc((size_t)MROWS * 128 * 2);
    ushort_t* he     = (ushort_t*)alloc((size_t)MROWS * 64 * 2);
    ushort_t* ein    = (ushort_t*)alloc((size_t)MROWS * 96 * 2);
    ushort_t* pn     = (ushort_t*)alloc((size_t)2048 * 128 * 2);
    ushort_t* nodesb = (ushort_t*)alloc((size_t)2 * NN * 64 * 2);
    int2*     ijt    = (int2*)alloc((size_t)NEDGE * 8);
    ushort_t* pan1 = (ushort_t*)alloc(160 * 256 * 2);
    ushort_t* pan2 = (ushort_t*)alloc(256 * 128 * 2);
    ushort_t* pae1 = (ushort_t*)alloc(96 * 128 * 2);
    ushort_t* pae2 = (ushort_t*)alloc(128 * 64 * 2);
    ushort_t* ple1 = (ushort_t*)alloc(96 * 96 * 2);
    ushort_t* ple2 = (ushort_t*)alloc(96 * 32 * 2);
    ushort_t* pln1 = (ushort_t*)alloc(192 * 192 * 2);
    ushort_t* pln2 = (ushort_t*)alloc(192 * 64 * 2);

    float* out_nodes = (float*)d_out;
    float* out_edges = (float*)d_out + 2 * NN * 64;

    k_pack<<<406, 256, 0, stream>>>(Wan1, Wan2, Wae1, Wae2, Wle1, Wle2, Wln1, Wln2,
                                    nodes,
                                    pan1, pan2, pae1, pae2, ple1, ple2, pln1, pln2,
                                    nodesb, ijt);
    k_agg<<<2015, 512, 0, stream>>>(nodesb, edges, ijt,
                                    pan1, ban1, pan2, ban2,
                                    pae1, bae1, pae2, bae2, hn, he);
    k_mid<<<4096, 256, 0, stream>>>(hn, he, edges, pn, ein);
    k_final<<<64 + 2015, 192, 0, stream>>>(pn, nodesb, pln1, bln1, pln2, bln2, out_nodes,
                                           ein, ple1, ble1, ple2, ble2, out_edges);

    (void)in_sizes; (void)n_in; (void)out_size; (void)ws_size;
}

// Round 11
// 165.053 us; speedup vs baseline: 1.1261x; 1.0278x over previous
//
#include <hip/hip_runtime.h>
#include <cstdint>

#define NN    1024
#define MM    32
#define NEDGE 32240
#define MROWS 64480   // 2*NEDGE
#define PX    168     // X tile pitch (ushorts)
#define PST   392     // unified stage pitch: 256 (H1n) + 128 (H1e) + 8 pad

typedef unsigned short ushort_t;

typedef __bf16 bf16x8 __attribute__((ext_vector_type(8)));
typedef float  floatx4 __attribute__((ext_vector_type(4)));

__device__ __forceinline__ float b2f(ushort_t u) {
    union { unsigned int i; float f; } v; v.i = ((unsigned int)u) << 16; return v.f;
}
__device__ __forceinline__ ushort_t f2b(float f) {
    unsigned int u = __builtin_bit_cast(unsigned int, f);
    u = (u + 0x7FFFu + ((u >> 16) & 1u)) >> 16;
    return (ushort_t)u;
}
// K(i): number of edges before node i
__device__ __forceinline__ int edge_base(int i) {
    return (i <= MM) ? ((i * (i - 1)) >> 1) : (496 + (i - MM) * MM);
}
// edge id e -> (dest i, src j)   [validated round 3; used only in pack]
__device__ __forceinline__ void edge_ij(int e, int& i, int& j) {
    if (e < 496) {
        i = (int)((1.0f + sqrtf(8.0f * (float)e + 1.0f)) * 0.5f);
        while (((i * (i - 1)) >> 1) > e) --i;
        while (((i * (i + 1)) >> 1) <= e) ++i;
        j = e - ((i * (i - 1)) >> 1);
    } else {
        int q = e - 496;
        i = MM + (q >> 5);
        j = i - MM + (q & 31);
    }
}

// ---------------- pack: weight transpose + nodes/edges bf16 + ij table ----------------
__global__ __launch_bounds__(256) void k_pack(
        const float* an1, const float* an2, const float* ae1, const float* ae2,
        const float* le1, const float* le2, const float* ln1, const float* ln2,
        const float* nodes, const float* edges,
        ushort_t* pan1, ushort_t* pan2, ushort_t* pae1, ushort_t* pae2,
        ushort_t* ple1, ushort_t* ple2, ushort_t* pln1, ushort_t* pln2,
        ushort_t* nodesb, ushort_t* edgesb, int2* ijt) {
    __shared__ float tile[32][33];
    const int bid = blockIdx.x;
    const int tid = threadIdx.x;
    if (bid < 152) {
        const float* s; ushort_t* d; int K, N, t;
        if (bid < 40)       { s = an1; d = pan1; K = 160; N = 256; t = bid;       }
        else if (bid < 72)  { s = an2; d = pan2; K = 256; N = 128; t = bid - 40;  }
        else if (bid < 84)  { s = ae1; d = pae1; K = 96;  N = 128; t = bid - 72;  }
        else if (bid < 92)  { s = ae2; d = pae2; K = 128; N = 64;  t = bid - 84;  }
        else if (bid < 101) { s = le1; d = ple1; K = 96;  N = 96;  t = bid - 92;  }
        else if (bid < 104) { s = le2; d = ple2; K = 96;  N = 32;  t = bid - 101; }
        else if (bid < 140) { s = ln1; d = pln1; K = 192; N = 192; t = bid - 104; }
        else                { s = ln2; d = pln2; K = 192; N = 64;  t = bid - 140; }
        int ntn = N >> 5;
        int tk = t / ntn, tn = t - tk * ntn;
        int k0 = tk * 32, n0 = tn * 32;
        int tx = tid & 31, ty = tid >> 5;
#pragma unroll
        for (int m = 0; m < 4; ++m)
            tile[ty + m * 8][tx] = s[(size_t)(k0 + ty + m * 8) * N + n0 + tx];
        __syncthreads();
#pragma unroll
        for (int m = 0; m < 4; ++m)
            d[(size_t)(n0 + ty + m * 8) * K + k0 + tx] = f2b(tile[tx][ty + m * 8]);
    } else if (bid < 280) {
        int i4 = (bid - 152) * 256 + tid;
        float4 v = ((const float4*)nodes)[i4];
        uint2 o;
        o.x = (unsigned)f2b(v.x) | ((unsigned)f2b(v.y) << 16);
        o.y = (unsigned)f2b(v.z) | ((unsigned)f2b(v.w) << 16);
        ((uint2*)nodesb)[i4] = o;
    } else if (bid < 2296) {
        int i4 = (bid - 280) * 256 + tid;
        if (i4 < 515840) {
            float4 v = ((const float4*)edges)[i4];
            uint2 o;
            o.x = (unsigned)f2b(v.x) | ((unsigned)f2b(v.y) << 16);
            o.y = (unsigned)f2b(v.z) | ((unsigned)f2b(v.w) << 16);
            ((uint2*)edgesb)[i4] = o;
        }
    } else {
        int e = (bid - 2296) * 256 + tid;
        if (e < NEDGE) { int i, j; edge_ij(e, i, j); ijt[e] = make_int2(i, j); }
    }
}

// ---------------- agg: merged node+edge branches, coalesced-store epilogue ----------------
// 512 thr = 8 waves. Stage1: wave w -> an1 tiles {w,w+8} + ae1 tile {w}. Stage2: waves 0-3 an2
// tiles {w,w+4}; waves 4-7 ae2 tile {w-4}. Output tiles staged in LDS, stored as dense uint4 rows.
__global__ __launch_bounds__(512, 2) void k_agg(
        const ushort_t* __restrict__ nodesb, const ushort_t* __restrict__ edgesb,
        const int2* __restrict__ ijt,
        const ushort_t* __restrict__ pan1, const float* __restrict__ ban1,
        const ushort_t* __restrict__ pan2, const float* __restrict__ ban2,
        const ushort_t* __restrict__ pae1, const float* __restrict__ bae1,
        const ushort_t* __restrict__ pae2, const float* __restrict__ bae2,
        ushort_t* __restrict__ hn, ushort_t* __restrict__ he) {
    __shared__ alignas(16) ushort_t X[32 * PX];     // X tile; reused as hn-stage (pitch 136)
    __shared__ alignas(16) ushort_t H[32 * PST];    // H1 tile; reused as he-stage (pitch 72)
    const int tid = threadIdx.x;
    const int w = tid >> 6, l = tid & 63, lrow = l & 15, lq = l >> 4;
    const int mt = blockIdx.x;
    floatx4 zero = {0.f, 0.f, 0.f, 0.f};

    // stage-1 B fragments (issued before gather for latency overlap)
    bf16x8 B0[5], B1[5], B2[3];
#pragma unroll
    for (int kt = 0; kt < 5; ++kt) {
        B0[kt] = *(const bf16x8*)(pan1 + (size_t)(16 * w + lrow) * 160 + kt * 32 + lq * 8);
        B1[kt] = *(const bf16x8*)(pan1 + (size_t)(16 * (w + 8) + lrow) * 160 + kt * 32 + lq * 8);
    }
#pragma unroll
    for (int kt = 0; kt < 3; ++kt)
        B2[kt] = *(const bf16x8*)(pae1 + (size_t)(16 * w + lrow) * 96 + kt * 32 + lq * 8);
    float c0 = ban1[16 * w + lrow];
    float c1 = ban1[16 * (w + 8) + lrow];
    float c2 = bae1[16 * w + lrow];

    // gather: wave w rows w*4..w*4+3, all-uint copies (edgesb pre-converted)
#pragma unroll
    for (int k = 0; k < 4; ++k) {
        int rr = w * 4 + k;
        int r = mt * 32 + rr;
        int off = (r >= NEDGE) ? 1 : 0;
        int2 ij = ijt[r - off * NEDGE];
        int bN = off * NN;
        unsigned* xr = (unsigned*)(X + rr * PX);
        const unsigned* nj = (const unsigned*)(nodesb + (size_t)(bN + ij.y) * 64);
        const unsigned* ni = (const unsigned*)(nodesb + (size_t)(bN + ij.x) * 64);
        const unsigned* eb = (const unsigned*)(edgesb + (size_t)r * 32);
        if (l < 32) { xr[l] = nj[l]; xr[48 + l] = ni[l]; }
        else        xr[l] = eb[l - 32];      // uints 32..47 = edge cols
    }
    __syncthreads();

    // stage 1: A shared per s across the wave's 3 tiles
#pragma unroll
    for (int s = 0; s < 2; ++s) {
        bf16x8 A[5];
#pragma unroll
        for (int kt = 0; kt < 5; ++kt)
            A[kt] = *(const bf16x8*)&X[(s * 16 + lrow) * PX + kt * 32 + lq * 8];
        floatx4 a0 = zero, a1 = zero, a2 = zero;
#pragma unroll
        for (int kt = 0; kt < 5; ++kt) {
            a0 = __builtin_amdgcn_mfma_f32_16x16x32_bf16(A[kt], B0[kt], a0, 0, 0, 0);
            a1 = __builtin_amdgcn_mfma_f32_16x16x32_bf16(A[kt], B1[kt], a1, 0, 0, 0);
        }
#pragma unroll
        for (int kt = 0; kt < 3; ++kt)
            a2 = __builtin_amdgcn_mfma_f32_16x16x32_bf16(A[kt], B2[kt], a2, 0, 0, 0);
#pragma unroll
        for (int r_ = 0; r_ < 4; ++r_) {
            int row = (s * 16 + lq * 4 + r_) * PST;
            H[row + 16 * w + lrow]       = f2b(fmaxf(a0[r_] + c0, 0.f));
            H[row + 128 + 16 * w + lrow] = f2b(fmaxf(a1[r_] + c1, 0.f));
            H[row + 256 + 16 * w + lrow] = f2b(fmaxf(a2[r_] + c2, 0.f));
        }
    }
    __syncthreads();

    // stage 2 compute (H reads finish before stage buffers are overwritten)
    floatx4 o0[2], o1[2];                    // node: an2 two tiles / edge: ae2 one tile in o0
    if (w < 4) {
        bf16x8 D0[8], D1[8];
#pragma unroll
        for (int kt = 0; kt < 8; ++kt) {
            D0[kt] = *(const bf16x8*)(pan2 + (size_t)(16 * w + lrow) * 256 + kt * 32 + lq * 8);
            D1[kt] = *(const bf16x8*)(pan2 + (size_t)(16 * (w + 4) + lrow) * 256 + kt * 32 + lq * 8);
        }
        float d0 = ban2[16 * w + lrow];
        float d1 = ban2[16 * (w + 4) + lrow];
#pragma unroll
        for (int s = 0; s < 2; ++s) {
            floatx4 a0 = zero, a1 = zero;
#pragma unroll
            for (int kt = 0; kt < 8; ++kt) {
                bf16x8 a = *(const bf16x8*)&H[(s * 16 + lrow) * PST + kt * 32 + lq * 8];
                a0 = __builtin_amdgcn_mfma_f32_16x16x32_bf16(a, D0[kt], a0, 0, 0, 0);
                a1 = __builtin_amdgcn_mfma_f32_16x16x32_bf16(a, D1[kt], a1, 0, 0, 0);
            }
#pragma unroll
            for (int r_ = 0; r_ < 4; ++r_) { o0[s][r_] = a0[r_] + d0; o1[s][r_] = a1[r_] + d1; }
        }
    } else {
        int u = w - 4;
        bf16x8 E[4];
#pragma unroll
        for (int kt = 0; kt < 4; ++kt)
            E[kt] = *(const bf16x8*)(pae2 + (size_t)(16 * u + lrow) * 128 + kt * 32 + lq * 8);
        float d2 = bae2[16 * u + lrow];
#pragma unroll
        for (int s = 0; s < 2; ++s) {
            floatx4 a2 = zero;
#pragma unroll
            for (int kt = 0; kt < 4; ++kt) {
                bf16x8 a = *(const bf16x8*)&H[(s * 16 + lrow) * PST + 256 + kt * 32 + lq * 8];
                a2 = __builtin_amdgcn_mfma_f32_16x16x32_bf16(a, E[kt], a2, 0, 0, 0);
            }
#pragma unroll
            for (int r_ = 0; r_ < 4; ++r_) o0[s][r_] = a2[r_] + d2;
        }
    }
    __syncthreads();

    // fragment -> LDS stage (hn in X region pitch 136; he in H region pitch 72)
    ushort_t* S = X;
    ushort_t* T = H;
    if (w < 4) {
#pragma unroll
        for (int s = 0; s < 2; ++s)
#pragma unroll
            for (int r_ = 0; r_ < 4; ++r_) {
                int row = (s * 16 + lq * 4 + r_) * 136;
                S[row + 16 * w + lrow]        = f2b(fmaxf(o0[s][r_], 0.f));
                S[row + 64 + 16 * w + lrow]   = f2b(fmaxf(o1[s][r_], 0.f));
            }
    } else {
        int u = w - 4;
#pragma unroll
        for (int s = 0; s < 2; ++s)
#pragma unroll
            for (int r_ = 0; r_ < 4; ++r_)
                T[(s * 16 + lq * 4 + r_) * 72 + 16 * u + lrow] = f2b(fmaxf(o0[s][r_], 0.f));
    }
    __syncthreads();

    // dense coalesced stores: hn 32 rows x 16 uint4 (512 chunks), he 32 x 8 (256 chunks)
    {
        int row = tid >> 4, c = tid & 15;
        ((uint4*)(hn + (size_t)(mt * 32 + row) * 128))[c] = *(const uint4*)&S[row * 136 + c * 8];
        if (tid < 256) {
            int row2 = tid >> 3, c2 = tid & 7;
            ((uint4*)(he + (size_t)(mt * 32 + row2) * 64))[c2] = *(const uint4*)&T[row2 * 72 + c2 * 8];
        }
    }
}

// ---------------- mid: pn = window-parallel mean(hn) | pre = prefix-mean(he), blockIdx split ----------------
__global__ __launch_bounds__(256) void k_mid(
        const ushort_t* __restrict__ hn, const ushort_t* __restrict__ he,
        ushort_t* __restrict__ pn, ushort_t* __restrict__ pre) {
    const int tid = threadIdx.x;
    if (blockIdx.x < 2048) {
        int ri = blockIdx.x;
        int b = ri >> 10, i = ri & 1023;
        int t = min(i, MM);
        int base = b * NEDGE + edge_base(i);
        int c = tid & 63, g = tid >> 6;
        float s0 = 0.f, s1 = 0.f;
        for (int p = g; p < t; p += 4) {
            unsigned u = ((const unsigned*)(hn + (size_t)(base + p) * 128))[c];
            s0 += b2f((ushort_t)(u & 0xffff));
            s1 += b2f((ushort_t)(u >> 16));
        }
        __shared__ float red[4][128];
        red[g][c * 2] = s0; red[g][c * 2 + 1] = s1;
        __syncthreads();
        if (tid < 64) {
            float inv = 1.0f / (float)max(t, 1);
            float a0 = (red[0][tid * 2] + red[1][tid * 2] + red[2][tid * 2] + red[3][tid * 2]) * inv;
            float a1 = (red[0][tid * 2 + 1] + red[1][tid * 2 + 1] + red[2][tid * 2 + 1] + red[3][tid * 2 + 1]) * inv;
            ((unsigned*)(pn + (size_t)ri * 128))[tid] = (unsigned)f2b(a0) | ((unsigned)f2b(a1) << 16);
        }
    } else {
        int bi = blockIdx.x - 2048;
        int b = bi >> 10, i = bi & 1023;
        int t = min(i, MM);
        if (t == 0) return;
        int base = b * NEDGE + edge_base(i);
        __shared__ alignas(16) ushort_t hw[32 * 64];
        for (int u = tid; u < t * 8; u += 256)
            ((uint4*)hw)[u] = ((const uint4*)he)[(size_t)base * 8 + u];
        __syncthreads();
        if (tid < 64) {
            float run = 0.f;
            for (int p = 0; p < t; ++p) {
                float v = (p == 0) ? 0.f : run / (float)p;
                pre[(size_t)(base + p) * 64 + tid] = f2b(v);
                run += b2f(hw[p * 64 + tid]);
            }
        }
    }
}

// ---------------- final: node MLP ([pn|nodesb] 192->192->64) | le12 ([pre|edgesb] 96->96->32) ----------------
__global__ __launch_bounds__(192) void k_final(
        const ushort_t* __restrict__ pn, const ushort_t* __restrict__ nodesb,
        const ushort_t* __restrict__ pln1, const float* __restrict__ bln1,
        const ushort_t* __restrict__ pln2, const float* __restrict__ bln2,
        float* __restrict__ out_nodes,
        const ushort_t* __restrict__ pre, const ushort_t* __restrict__ edgesb,
        const ushort_t* __restrict__ ple1, const float* __restrict__ ble1,
        const ushort_t* __restrict__ ple2, const float* __restrict__ ble2,
        float* __restrict__ out_edges) {
    __shared__ alignas(16) ushort_t LA[32 * 200];
    __shared__ alignas(16) ushort_t LB[32 * 200];
    const int tid = threadIdx.x;
    const int w = tid >> 6, l = tid & 63, lrow = l & 15, lq = l >> 4;
    floatx4 zero = {0.f, 0.f, 0.f, 0.f};

    if (blockIdx.x < 64) {
        int tile = blockIdx.x;
        for (int u = tid; u < 768; u += 192) {        // 32 rows x 24 uint4 chunks
            int row = u / 24, c = u - row * 24;
            int r = tile * 32 + row;
            const uint4* src = (c < 16) ? ((const uint4*)(pn + (size_t)r * 128) + c)
                                        : ((const uint4*)(nodesb + (size_t)r * 64) + (c - 16));
            *(uint4*)&LA[row * 200 + c * 8] = *src;
        }
        bf16x8 f1[6][4]; float v1[4];
#pragma unroll
        for (int kt = 0; kt < 6; ++kt)
#pragma unroll
            for (int nt = 0; nt < 4; ++nt)
                f1[kt][nt] = *(const bf16x8*)(pln1 + (size_t)(w * 64 + nt * 16 + lrow) * 192 + kt * 32 + lq * 8);
#pragma unroll
        for (int nt = 0; nt < 4; ++nt) v1[nt] = bln1[w * 64 + nt * 16 + lrow];
        __syncthreads();

        floatx4 acc[2][4];
#pragma unroll
        for (int s = 0; s < 2; ++s)
#pragma unroll
            for (int nt = 0; nt < 4; ++nt) acc[s][nt] = zero;
#pragma unroll
        for (int s = 0; s < 2; ++s)
#pragma unroll
            for (int kt = 0; kt < 6; ++kt) {
                bf16x8 a = *(const bf16x8*)&LA[(s * 16 + lrow) * 200 + kt * 32 + lq * 8];
#pragma unroll
                for (int nt = 0; nt < 4; ++nt)
                    acc[s][nt] = __builtin_amdgcn_mfma_f32_16x16x32_bf16(a, f1[kt][nt], acc[s][nt], 0, 0, 0);
            }
#pragma unroll
        for (int s = 0; s < 2; ++s)
#pragma unroll
            for (int nt = 0; nt < 4; ++nt) {
                int col = w * 64 + nt * 16 + lrow;
#pragma unroll
                for (int r_ = 0; r_ < 4; ++r_)
                    LB[(s * 16 + lq * 4 + r_) * 200 + col] = f2b(fmaxf(acc[s][nt][r_] + v1[nt], 0.f));
            }
        bf16x8 f2[6][2]; float v2[2] = {0.f, 0.f};
        if (w < 2) {
#pragma unroll
            for (int kt = 0; kt < 6; ++kt)
#pragma unroll
                for (int nt = 0; nt < 2; ++nt)
                    f2[kt][nt] = *(const bf16x8*)(pln2 + (size_t)(w * 32 + nt * 16 + lrow) * 192 + kt * 32 + lq * 8);
#pragma unroll
            for (int nt = 0; nt < 2; ++nt) v2[nt] = bln2[w * 32 + nt * 16 + lrow];
        }
        __syncthreads();
        if (w < 2) {
            floatx4 a2[2][2];
#pragma unroll
            for (int s = 0; s < 2; ++s) { a2[s][0] = zero; a2[s][1] = zero; }
#pragma unroll
            for (int s = 0; s < 2; ++s)
#pragma unroll
                for (int kt = 0; kt < 6; ++kt) {
                    bf16x8 a = *(const bf16x8*)&LB[(s * 16 + lrow) * 200 + kt * 32 + lq * 8];
#pragma unroll
                    for (int nt = 0; nt < 2; ++nt)
                        a2[s][nt] = __builtin_amdgcn_mfma_f32_16x16x32_bf16(a, f2[kt][nt], a2[s][nt], 0, 0, 0);
                }
#pragma unroll
            for (int s = 0; s < 2; ++s)
#pragma unroll
                for (int nt = 0; nt < 2; ++nt) {
                    int col = w * 32 + nt * 16 + lrow;
#pragma unroll
                    for (int r_ = 0; r_ < 4; ++r_)
                        out_nodes[(size_t)(tile * 32 + s * 16 + lq * 4 + r_) * 64 + col] =
                            fmaxf(a2[s][nt][r_] + v2[nt], 0.f);
                }
        }
    } else {
        int mt = blockIdx.x - 64;
        // stage [pre(8) | edgesb(4)] chunks per row, pitch 104
        for (int u = tid; u < 384; u += 192) {
            int row = u / 12, c = u - row * 12;
            int r = mt * 32 + row;
            const uint4* src = (c < 8) ? ((const uint4*)(pre + (size_t)r * 64) + c)
                                       : ((const uint4*)(edgesb + (size_t)r * 32) + (c - 8));
            *(uint4*)&LA[row * 104 + c * 8] = *src;
        }
        bf16x8 fb1[3][2]; float v1[2];
#pragma unroll
        for (int kt = 0; kt < 3; ++kt)
#pragma unroll
            for (int nt = 0; nt < 2; ++nt)
                fb1[kt][nt] = *(const bf16x8*)(ple1 + (size_t)(w * 32 + nt * 16 + lrow) * 96 + kt * 32 + lq * 8);
#pragma unroll
        for (int nt = 0; nt < 2; ++nt) v1[nt] = ble1[w * 32 + nt * 16 + lrow];
        bf16x8 fb2[3]; float v2 = 0.f;
        if (w < 2) {
#pragma unroll
            for (int kt = 0; kt < 3; ++kt)
                fb2[kt] = *(const bf16x8*)(ple2 + (size_t)(w * 16 + lrow) * 96 + kt * 32 + lq * 8);
            v2 = ble2[w * 16 + lrow];
        }
        __syncthreads();

        floatx4 acc[2][2];
#pragma unroll
        for (int s = 0; s < 2; ++s) { acc[s][0] = zero; acc[s][1] = zero; }
#pragma unroll
        for (int s = 0; s < 2; ++s)
#pragma unroll
            for (int kt = 0; kt < 3; ++kt) {
                bf16x8 a = *(const bf16x8*)&LA[(s * 16 + lrow) * 104 + kt * 32 + lq * 8];
#pragma unroll
                for (int nt = 0; nt < 2; ++nt)
                    acc[s][nt] = __builtin_amdgcn_mfma_f32_16x16x32_bf16(a, fb1[kt][nt], acc[s][nt], 0, 0, 0);
            }
#pragma unroll
        for (int s = 0; s < 2; ++s)
#pragma unroll
            for (int nt = 0; nt < 2; ++nt) {
                int col = w * 32 + nt * 16 + lrow;
#pragma unroll
                for (int r_ = 0; r_ < 4; ++r_)
                    LB[(s * 16 + lq * 4 + r_) * 104 + col] = f2b(fmaxf(acc[s][nt][r_] + v1[nt], 0.f));
            }
        __syncthreads();
        if (w < 2) {
            floatx4 a2[2] = {zero, zero};
#pragma unroll
            for (int s = 0; s < 2; ++s)
#pragma unroll
                for (int kt = 0; kt < 3; ++kt) {
                    bf16x8 a = *(const bf16x8*)&LB[(s * 16 + lrow) * 104 + kt * 32 + lq * 8];
                    a2[s] = __builtin_amdgcn_mfma_f32_16x16x32_bf16(a, fb2[kt], a2[s], 0, 0, 0);
                }
#pragma unroll
            for (int s = 0; s < 2; ++s) {
                int col = w * 16 + lrow;
#pragma unroll
                for (int r_ = 0; r_ < 4; ++r_)
                    out_edges[(size_t)(mt * 32 + s * 16 + lq * 4 + r_) * 32 + col] = fmaxf(a2[s][r_] + v2, 0.f);
            }
        }
    }
}

extern "C" void kernel_launch(void* const* d_in, const int* in_sizes, int n_in,
                              void* d_out, int out_size, void* d_ws, size_t ws_size,
                              hipStream_t stream) {
    const float* nodes = (const float*)d_in[0];
    const float* edges = (const float*)d_in[1];
    const float* Wan1 = (const float*)d_in[2];  const float* ban1 = (const float*)d_in[3];
    const float* Wan2 = (const float*)d_in[4];  const float* ban2 = (const float*)d_in[5];
    const float* Wln1 = (const float*)d_in[6];  const float* bln1 = (const float*)d_in[7];
    const float* Wln2 = (const float*)d_in[8];  const float* bln2 = (const float*)d_in[9];
    const float* Wae1 = (const float*)d_in[10]; const float* bae1 = (const float*)d_in[11];
    const float* Wae2 = (const float*)d_in[12]; const float* bae2 = (const float*)d_in[13];
    const float* Wle1 = (const float*)d_in[14]; const float* ble1 = (const float*)d_in[15];
    const float* Wle2 = (const float*)d_in[16]; const float* ble2 = (const float*)d_in[17];

    char* ws = (char*)d_ws;
    size_t o = 0;
    auto alloc = [&](size_t bytes) -> void* {
        void* r = ws + o;
        o += (bytes + 255) & ~(size_t)255;
        return r;
    };
    ushort_t* hn     = (ushort_t*)alloc((size_t)MROWS * 128 * 2);
    ushort_t* he     = (ushort_t*)alloc((size_t)MROWS * 64 * 2);
    ushort_t* pre    = (ushort_t*)alloc((size_t)MROWS * 64 * 2);
    ushort_t* pn     = (ushort_t*)alloc((size_t)2048 * 128 * 2);
    ushort_t* nodesb = (ushort_t*)alloc((size_t)2 * NN * 64 * 2);
    ushort_t* edgesb = (ushort_t*)alloc((size_t)MROWS * 32 * 2);
    int2*     ijt    = (int2*)alloc((size_t)NEDGE * 8);
    ushort_t* pan1 = (ushort_t*)alloc(160 * 256 * 2);
    ushort_t* pan2 = (ushort_t*)alloc(256 * 128 * 2);
    ushort_t* pae1 = (ushort_t*)alloc(96 * 128 * 2);
    ushort_t* pae2 = (ushort_t*)alloc(128 * 64 * 2);
    ushort_t* ple1 = (ushort_t*)alloc(96 * 96 * 2);
    ushort_t* ple2 = (ushort_t*)alloc(96 * 32 * 2);
    ushort_t* pln1 = (ushort_t*)alloc(192 * 192 * 2);
    ushort_t* pln2 = (ushort_t*)alloc(192 * 64 * 2);

    float* out_nodes = (float*)d_out;
    float* out_edges = (float*)d_out + 2 * NN * 64;

    k_pack<<<2422, 256, 0, stream>>>(Wan1, Wan2, Wae1, Wae2, Wle1, Wle2, Wln1, Wln2,
                                     nodes, edges,
                                     pan1, pan2, pae1, pae2, ple1, ple2, pln1, pln2,
                                     nodesb, edgesb, ijt);
    k_agg<<<2015, 512, 0, stream>>>(nodesb, edgesb, ijt,
                                    pan1, ban1, pan2, ban2,
                                    pae1, bae1, pae2, bae2, hn, he);
    k_mid<<<4096, 256, 0, stream>>>(hn, he, pn, pre);
    k_final<<<64 + 2015, 192, 0, stream>>>(pn, nodesb, pln1, bln1, pln2, bln2, out_nodes,
                                           pre, edgesb, ple1, ble1, ple2, ble2, out_edges);

    (void)in_sizes; (void)n_in; (void)out_size; (void)ws_size;
}